// Round 10
// baseline (416.959 us; speedup 1.0000x reference)
//
#include <hip/hip_runtime.h>
#include <hip/hip_bf16.h>

// scores[b,t] = sum_u tanh((source@W1)[b,u] + (target@W2)[b,t,u]) * a[u]
// B=64 T=8192 D=256 U=128. Memory-bound: 537MB target read; ~86us floor at 6.3TB/s.
// Round 10: R4's structure with the live set designed to fit the allocator's
// hard VGPR=64 target (R1/R7 proved launch-bounds/waves_per_eu do NOT raise it;
// R2-R5/R9 live sets were 75-95 regs => silent spill; R4's 5.0TB/s on ideal bytes
// ~= 6.2TB/s on ideal+spill bytes). Payload granularity k-quarter -> k-eighth:
// 2 sets x 8 regs = 16 (was 48), acc 32, af 4, temps ~10 => ~62 live. Same scatter
// pattern, same ds_read:MFMA ratio, depth-2, no barriers in the main loop.

#define B_ 64
#define T_ 8192
#define D_ 256
#define U_ 128
#define LDSW 264   // W2 LDS stride (bf16): 528B rows -> bank-uniform b128 frag reads

typedef __attribute__((ext_vector_type(8))) short bf16x8;
typedef __attribute__((ext_vector_type(4))) float f32x4;

__device__ __forceinline__ short f2bf(float f) {
    unsigned u = __builtin_bit_cast(unsigned, f);
    u += 0x7fffu + ((u >> 16) & 1u);   // RTNE
    return (short)(u >> 16);
}

__device__ __forceinline__ float fast_tanh(float x) {
    float e = __expf(2.0f * x);
    return 1.0f - 2.0f * __builtin_amdgcn_rcpf(e + 1.0f);
}

__device__ __forceinline__ bf16x8 cvt8(const float4& a, const float4& b) {
    union { __hip_bfloat162 h[4]; bf16x8 v; } u;
    u.h[0] = __float22bfloat162_rn(make_float2(a.x, a.y));
    u.h[1] = __float22bfloat162_rn(make_float2(a.z, a.w));
    u.h[2] = __float22bfloat162_rn(make_float2(b.x, b.y));
    u.h[3] = __float22bfloat162_rn(make_float2(b.z, b.w));
    return u.v;
}

__global__ __launch_bounds__(512) void additive_attn_kernel(
        const float* __restrict__ target,
        const float* __restrict__ source,
        const float* __restrict__ W1,
        const float* __restrict__ W2,
        const float* __restrict__ attn,
        float* __restrict__ out) {
    __shared__ __attribute__((aligned(16))) short lds_w2[U_ * LDSW];  // 67.6 KB
    __shared__ float  lds_red[512];
    __shared__ __attribute__((aligned(16))) float2 lds_sa[U_];        // {s_u, a_u}

    const int tid  = threadIdx.x;
    const int bx   = blockIdx.x;
    const int b    = bx >> 3;            // 8 blocks per batch element
    const int tb   = (bx & 7) << 10;     // 1024 rows per block

    const int lane = tid & 63;
    const int wave = tid >> 6;           // 0..7
    const int c    = lane & 15;
    const int g    = lane >> 4;

    const float* tgt  = target + ((size_t)b * T_ + tb) * D_;
    float*       outp = out + (size_t)b * T_ + tb;
    const float* Abase = tgt + (size_t)(wave * 16 + c) * D_ + g * 8;

    // 2 payload sets x one k-eighth (row c, 8 floats): 16 VGPRs total
    float4 xa0, xa1, xb0, xb1;

    // step S (0..63): row-tile rt=S>>3 (128 rows), k-eighth e=S&7.
    // lane (c,g) reads row rt*128+wave*16+c, k = e*32 + g*8 + [0,8)
#define LOADE(X0, X1, S) do {                                                 \
    const float* p_ = Abase + (size_t)((S) >> 3) * (128 * D_) + ((S) & 7) * 32; \
    X0 = *(const float4*)(p_);                                                \
    X1 = *(const float4*)(p_ + 4);                                            \
} while (0)

    LOADE(xa0, xa1, 0);   // prime depth-2; in flight across the prologue
    LOADE(xb0, xb1, 1);

    // --- stage W2: fp32 [D][U] -> bf16 LDS [u][d], b128 writes ---
    {
        const int u    = tid & (U_ - 1);
        const int dblk = (tid >> 7) << 6;    // 0,64,128,192
        #pragma unroll
        for (int w = 0; w < 8; ++w) {
            const int d0 = dblk + w * 8;
            bf16x8 v;
            #pragma unroll
            for (int i = 0; i < 8; ++i)
                v[i] = f2bf(W2[(size_t)(d0 + i) * U_ + u]);
            *(bf16x8*)&lds_w2[u * LDSW + d0] = v;
        }
    }

    // --- s[u] = (source[b] @ W1)[u], 4-way D split ---
    {
        const float* src = source + b * D_;
        const int u    = tid & (U_ - 1);
        const int part = tid >> 7;
        float a1 = 0.f;
        #pragma unroll 8
        for (int d = part * 64; d < part * 64 + 64; ++d)
            a1 = fmaf(src[d], W1[(size_t)d * U_ + u], a1);
        lds_red[tid] = a1;
    }
    __syncthreads();
    if (tid < U_)
        lds_sa[tid] = make_float2(
            lds_red[tid] + lds_red[tid + 128] + lds_red[tid + 256] + lds_red[tid + 384],
            attn[tid]);
    __syncthreads();

    f32x4 acc[8];
    #pragma unroll
    for (int j = 0; j < 8; ++j) acc[j] = (f32x4){0.f, 0.f, 0.f, 0.f};

    // epilogue: lane (c,g) holds t[row][u=16j+4g+r] in acc[j][r]
#define EPI(RT) do {                                                          \
    float sc = 0.f;                                                           \
    _Pragma("unroll")                                                         \
    for (int j = 0; j < 8; ++j) {                                             \
        const float4 sa01 = *(const float4*)&lds_sa[16 * j + 4 * g];          \
        const float4 sa23 = *(const float4*)&lds_sa[16 * j + 4 * g + 2];      \
        sc += fast_tanh(acc[j][0] + sa01.x) * sa01.y;                         \
        sc += fast_tanh(acc[j][1] + sa01.z) * sa01.w;                         \
        sc += fast_tanh(acc[j][2] + sa23.x) * sa23.y;                         \
        sc += fast_tanh(acc[j][3] + sa23.z) * sa23.w;                         \
        acc[j] = (f32x4){0.f, 0.f, 0.f, 0.f};                                 \
    }                                                                         \
    sc += __shfl_xor(sc, 16);                                                 \
    sc += __shfl_xor(sc, 32);                                                 \
    if (lane < 16) outp[(RT) * 128 + wave * 16 + lane] = sc;                  \
} while (0)

    // 64 steps = 8 row-tiles x 8 k-eighths; depth-2 register pipeline.
    // Per step: cvt (frees buffer) -> issue step+2 -> 8 x (ds_read_b128 + MFMA).
    #pragma unroll
    for (int s = 0; s < 64; ++s) {
        bf16x8 af;
        if ((s & 1) == 0) {
            af = cvt8(xa0, xa1);
            if (s < 62) LOADE(xa0, xa1, s + 2);
        } else {
            af = cvt8(xb0, xb1);
            if (s < 62) LOADE(xb0, xb1, s + 2);
        }
        const int kb = (s & 7) * 32 + g * 8;
        #pragma unroll
        for (int j = 0; j < 8; ++j) {
            bf16x8 wfj = *(const bf16x8*)&lds_w2[(16 * j + c) * LDSW + kb];
            acc[j] = __builtin_amdgcn_mfma_f32_16x16x32_bf16(wfj, af, acc[j], 0, 0, 0);
        }
        if ((s & 7) == 7) EPI(s >> 3);
    }

#undef LOADE
#undef EPI
}

extern "C" void kernel_launch(void* const* d_in, const int* in_sizes, int n_in,
                              void* d_out, int out_size, void* d_ws, size_t ws_size,
                              hipStream_t stream) {
    const float* target = (const float*)d_in[0];
    const float* source = (const float*)d_in[1];
    const float* W1     = (const float*)d_in[2];
    const float* W2     = (const float*)d_in[3];
    const float* attn   = (const float*)d_in[4];
    float* out = (float*)d_out;

    dim3 grid(B_ * (T_ / 1024));   // 512 blocks = 2 per CU
    dim3 block(512);
    hipLaunchKernelGGL(additive_attn_kernel, grid, block, 0, stream,
                       target, source, W1, W2, attn, out);
}

// Round 12
// 316.725 us; speedup vs baseline: 1.3165x; 1.3165x over previous
//
#include <hip/hip_runtime.h>
#include <hip/hip_bf16.h>

// scores[b,t] = sum_u tanh((source@W1)[b,u] + (target@W2)[b,t,u]) * a[u]
// B=64 T=8192 D=256 U=128. Memory-bound: 537MB target read; ~86us floor at 6.3TB/s.
// Round 12: R11 with the refill-distance bug fixed. R11's steps refilled the
// 2-set payload 4 quarters ahead, so steps 2,3 consumed the NEXT tile's data
// (absmax 44.9). Correct invariant for 2 sets: refill with quarter+2 (consume
// at step s, refill at s with q+2, consume again at s+2). Everything else as
// R11: dynamic outer loop fences scheduler hoisting (R10: full unroll -> live
// >128 -> 206MB spill), payload 2x16 regs, acc 32, plain launch_bounds(512)
// (R10 proved this yields VGPR=128).

#define B_ 64
#define T_ 8192
#define D_ 256
#define U_ 128
#define LDSW 264   // W2 LDS stride (bf16): 528B rows -> bank-uniform b128 frag reads

typedef __attribute__((ext_vector_type(8))) short bf16x8;
typedef __attribute__((ext_vector_type(4))) float f32x4;

__device__ __forceinline__ short f2bf(float f) {
    unsigned u = __builtin_bit_cast(unsigned, f);
    u += 0x7fffu + ((u >> 16) & 1u);   // RTNE
    return (short)(u >> 16);
}

__device__ __forceinline__ float fast_tanh(float x) {
    float e = __expf(2.0f * x);
    return 1.0f - 2.0f * __builtin_amdgcn_rcpf(e + 1.0f);
}

__device__ __forceinline__ bf16x8 cvt8(const float4& a, const float4& b) {
    union { __hip_bfloat162 h[4]; bf16x8 v; } u;
    u.h[0] = __float22bfloat162_rn(make_float2(a.x, a.y));
    u.h[1] = __float22bfloat162_rn(make_float2(a.z, a.w));
    u.h[2] = __float22bfloat162_rn(make_float2(b.x, b.y));
    u.h[3] = __float22bfloat162_rn(make_float2(b.z, b.w));
    return u.v;
}

__global__ __launch_bounds__(512) void additive_attn_kernel(
        const float* __restrict__ target,
        const float* __restrict__ source,
        const float* __restrict__ W1,
        const float* __restrict__ W2,
        const float* __restrict__ attn,
        float* __restrict__ out) {
    __shared__ __attribute__((aligned(16))) short lds_w2[U_ * LDSW];  // 67.6 KB
    __shared__ float  lds_red[512];
    __shared__ __attribute__((aligned(16))) float2 lds_sa[U_];        // {s_u, a_u}

    const int tid  = threadIdx.x;
    const int bx   = blockIdx.x;
    const int b    = bx >> 3;            // 8 blocks per batch element
    const int tb   = (bx & 7) << 10;     // 1024 rows per block

    const int lane = tid & 63;
    const int wave = tid >> 6;           // 0..7
    const int c    = lane & 15;
    const int g    = lane >> 4;

    const float* tgt  = target + ((size_t)b * T_ + tb) * D_;
    float*       outp = out + (size_t)b * T_ + tb;
    const float* Abase = tgt + (size_t)(wave * 16 + c) * D_ + g * 8;

    // 2 payload sets x one k-quarter (row c, 2x8 floats 128B apart): 32 VGPRs
    float4 a0, a1, a2, a3, b0, b1, b2, b3;

    // global quarter NQ (0..31): row-tile NQ>>2, k-quarter NQ&3.
    // lane (c,g): row (NQ>>2)*128 + wave*16 + c, k = (NQ&3)*64 + g*8 + {0..8, 32..40}
#define LOADQ(X0, X1, X2, X3, NQ) do {                                        \
    const float* p_ = Abase + (size_t)((NQ) >> 2) * (128 * D_) + ((NQ) & 3) * 64; \
    X0 = *(const float4*)(p_);      X1 = *(const float4*)(p_ + 4);            \
    X2 = *(const float4*)(p_ + 32); X3 = *(const float4*)(p_ + 36);           \
} while (0)

    LOADQ(a0, a1, a2, a3, 0);   // prime depth-2; in flight across the prologue
    LOADQ(b0, b1, b2, b3, 1);

    // --- stage W2: fp32 [D][U] -> bf16 LDS [u][d], b128 writes ---
    {
        const int u    = tid & (U_ - 1);
        const int dblk = (tid >> 7) << 6;    // 0,64,128,192
        #pragma unroll
        for (int w = 0; w < 8; ++w) {
            const int d0 = dblk + w * 8;
            bf16x8 v;
            #pragma unroll
            for (int i = 0; i < 8; ++i)
                v[i] = f2bf(W2[(size_t)(d0 + i) * U_ + u]);
            *(bf16x8*)&lds_w2[u * LDSW + d0] = v;
        }
    }

    // --- s[u] = (source[b] @ W1)[u], 4-way D split ---
    {
        const float* src = source + b * D_;
        const int u    = tid & (U_ - 1);
        const int part = tid >> 7;
        float s1 = 0.f;
        #pragma unroll 8
        for (int d = part * 64; d < part * 64 + 64; ++d)
            s1 = fmaf(src[d], W1[(size_t)d * U_ + u], s1);
        lds_red[tid] = s1;
    }
    __syncthreads();
    if (tid < U_)
        lds_sa[tid] = make_float2(
            lds_red[tid] + lds_red[tid + 128] + lds_red[tid + 256] + lds_red[tid + 384],
            attn[tid]);
    __syncthreads();

    f32x4 acc[8];
    #pragma unroll
    for (int j = 0; j < 8; ++j) acc[j] = (f32x4){0.f, 0.f, 0.f, 0.f};

    // A-op = W2 frag (m = u-in-tile), B-op = target frag (n = row c)
#define MFMAQ(AF0, AF1, Q) do {                                               \
    const int kb_ = (Q) * 64 + g * 8;                                         \
    _Pragma("unroll")                                                         \
    for (int j = 0; j < 8; ++j) {                                             \
        bf16x8 w0 = *(const bf16x8*)&lds_w2[(16 * j + c) * LDSW + kb_];       \
        acc[j] = __builtin_amdgcn_mfma_f32_16x16x32_bf16(w0, AF0, acc[j], 0, 0, 0); \
        bf16x8 w1 = *(const bf16x8*)&lds_w2[(16 * j + c) * LDSW + kb_ + 32];  \
        acc[j] = __builtin_amdgcn_mfma_f32_16x16x32_bf16(w1, AF1, acc[j], 0, 0, 0); \
    }                                                                         \
} while (0)

    // one quarter-step: cvt (frees buffer) -> issue refill (quarter+2) -> 16 MFMA
#define STEPQ(X0, X1, X2, X3, Q, NQ, GUARD) do {                              \
    bf16x8 af0 = cvt8(X0, X1);                                                \
    bf16x8 af1 = cvt8(X2, X3);                                                \
    if (GUARD) LOADQ(X0, X1, X2, X3, NQ);                                     \
    MFMAQ(af0, af1, Q);                                                       \
} while (0)

    // Dynamic loop over 8 row-tiles. Set A holds even quarters, set B odd.
    // Step s consumes global quarter gq+s and refills its set with gq+s+2:
    //   s=0: consume gq+0 (A), refill A <- gq+2
    //   s=1: consume gq+1 (B), refill B <- gq+3
    //   s=2: consume gq+2 (A), refill A <- gq+4   [tile boundary crossing]
    //   s=3: consume gq+3 (B), refill B <- gq+5
    for (int rt = 0; rt < 8; ++rt) {
        const int gq = rt * 4;
        STEPQ(a0, a1, a2, a3, 0, gq + 2, 1);
        STEPQ(b0, b1, b2, b3, 1, gq + 3, 1);
        STEPQ(a0, a1, a2, a3, 2, gq + 4, rt < 7);
        STEPQ(b0, b1, b2, b3, 3, gq + 5, rt < 7);

        // epilogue: lane (c,g) holds t[row][u=16j+4g+r] in acc[j][r]
        float sc = 0.f;
        #pragma unroll
        for (int j = 0; j < 8; ++j) {
            const float4 sa01 = *(const float4*)&lds_sa[16 * j + 4 * g];
            const float4 sa23 = *(const float4*)&lds_sa[16 * j + 4 * g + 2];
            sc += fast_tanh(acc[j][0] + sa01.x) * sa01.y;
            sc += fast_tanh(acc[j][1] + sa01.z) * sa01.w;
            sc += fast_tanh(acc[j][2] + sa23.x) * sa23.y;
            sc += fast_tanh(acc[j][3] + sa23.z) * sa23.w;
            acc[j] = (f32x4){0.f, 0.f, 0.f, 0.f};
        }
        sc += __shfl_xor(sc, 16);
        sc += __shfl_xor(sc, 32);
        if (lane < 16) outp[rt * 128 + wave * 16 + lane] = sc;
    }

#undef LOADQ
#undef MFMAQ
#undef STEPQ
}

extern "C" void kernel_launch(void* const* d_in, const int* in_sizes, int n_in,
                              void* d_out, int out_size, void* d_ws, size_t ws_size,
                              hipStream_t stream) {
    const float* target = (const float*)d_in[0];
    const float* source = (const float*)d_in[1];
    const float* W1     = (const float*)d_in[2];
    const float* W2     = (const float*)d_in[3];
    const float* attn   = (const float*)d_in[4];
    float* out = (float*)d_out;

    dim3 grid(B_ * (T_ / 1024));   // 512 blocks = 2 per CU
    dim3 block(512);
    hipLaunchKernelGGL(additive_attn_kernel, grid, block, 0, stream,
                       target, source, W1, W2, attn, out);
}